// Round 6
// baseline (188.803 us; speedup 1.0000x reference)
//
#include <hip/hip_runtime.h>
#include <math.h>

#define BLOCK 256
#define VEC   8
#define TILE  (BLOCK * VEC)   // 2048 elements per block
#define KW    5
// conv pad = 2 each; two stacked convs -> receptive field of out[i] is x[i-4 .. i+4].
// Each thread computes 8 outputs from x[i-4 .. i+11] (four aligned float4 loads),
// recomputing h[i-2 .. i+9] in registers. No LDS, no barriers.

typedef float f32x4 __attribute__((ext_vector_type(4)));

__global__ __launch_bounds__(BLOCK) void wav_attn_kernel(
    const float* __restrict__ x,
    const float* __restrict__ w1,
    const float* __restrict__ b1,
    const float* __restrict__ w2,
    const float* __restrict__ b2,
    float* __restrict__ out,
    int C, int L)
{
    const int row = blockIdx.y;          // b*C + c
    const int c   = row % C;
    const long long base = (long long)row * L;
    const int i   = blockIdx.x * TILE + threadIdx.x * VEC;
    if (i >= L) return;

    // per-channel weights: block-uniform address -> scalar (s_load) path
    float W1[KW], W2[KW];
    #pragma unroll
    for (int k = 0; k < KW; ++k) {
        W1[k] = w1[c * KW + k];
        W2[k] = w2[c * KW + k];
    }
    const float B1 = b1[c];
    const float B2 = b2[c];

    // ---- load x[i-4 .. i+11] into a[0..15] ----
    float a[16];
    if (i >= 4 && i + 11 < L) {
        // i is a multiple of 8 -> all four loads are 16B-aligned
        f32x4 v0 = *reinterpret_cast<const f32x4*>(x + base + i - 4);
        f32x4 v1 = *reinterpret_cast<const f32x4*>(x + base + i);
        f32x4 v2 = *reinterpret_cast<const f32x4*>(x + base + i + 4);
        f32x4 v3 = *reinterpret_cast<const f32x4*>(x + base + i + 8);
        #pragma unroll
        for (int e = 0; e < 4; ++e) {
            a[e]      = v0[e];
            a[4 + e]  = v1[e];
            a[8 + e]  = v2[e];
            a[12 + e] = v3[e];
        }
    } else {
        #pragma unroll
        for (int e = 0; e < 16; ++e) {
            int g = i - 4 + e;
            a[e] = (g >= 0 && g < L) ? x[base + g] : 0.f;
        }
    }

    // ---- h[j] = LeakyReLU(conv1)(x) at position p = i + j - 2, j = 0..11 ----
    // conv2's zero-padding applies to h: force 0 outside [0, L)
    float h[12];
    #pragma unroll
    for (int j = 0; j < 12; ++j) {
        int p = i + j - 2;
        float acc = B1;
        #pragma unroll
        for (int k = 0; k < KW; ++k)
            acc = fmaf(W1[k], a[j + k], acc);   // x[p+k-2] = a[j+k]
        acc = (acc >= 0.f) ? acc : 0.01f * acc;
        h[j] = (p >= 0 && p < L) ? acc : 0.f;
    }

    // ---- out[i+e] = x[i+e] * sigmoid(conv2(h)) ----
    float res[VEC];
    #pragma unroll
    for (int e = 0; e < VEC; ++e) {
        float z = B2;
        #pragma unroll
        for (int k = 0; k < KW; ++k)
            z = fmaf(W2[k], h[e + k], z);       // h[i+e+k-2] = h[e+k]
        float s = __builtin_amdgcn_rcpf(1.f + __expf(-z));
        res[e] = a[4 + e] * s;
    }

    if (i + VEC - 1 < L) {
        // out written once, never read: non-temporal keeps x resident in L2/L3
        f32x4 r0 = { res[0], res[1], res[2], res[3] };
        f32x4 r1 = { res[4], res[5], res[6], res[7] };
        __builtin_nontemporal_store(r0, reinterpret_cast<f32x4*>(out + base + i));
        __builtin_nontemporal_store(r1, reinterpret_cast<f32x4*>(out + base + i + 4));
    } else {
        #pragma unroll
        for (int e = 0; e < VEC; ++e)
            if (i + e < L) out[base + i + e] = res[e];
    }
}

extern "C" void kernel_launch(void* const* d_in, const int* in_sizes, int n_in,
                              void* d_out, int out_size, void* d_ws, size_t ws_size,
                              hipStream_t stream) {
    const float* x  = (const float*)d_in[0];
    const float* w1 = (const float*)d_in[1];
    const float* b1 = (const float*)d_in[2];
    const float* w2 = (const float*)d_in[3];
    const float* b2 = (const float*)d_in[4];
    float* out = (float*)d_out;

    const int C = in_sizes[2];               // 20
    const int B = 128;
    const int L = in_sizes[0] / (B * C);     // 10000

    dim3 grid((L + TILE - 1) / TILE, B * C); // 5 x 2560 blocks
    wav_attn_kernel<<<grid, BLOCK, 0, stream>>>(x, w1, b1, w2, b2, out, C, L);
}